// Round 8
// baseline (1019.390 us; speedup 1.0000x reference)
//
#include <hip/hip_runtime.h>
#include <hip/hip_bf16.h>
#include <cstdint>
#include <cstddef>

#define N_NODES 10000
#define M_PAD   10112   // N_NODES rounded up to 128
#define N_EDGES 60000
#define ETOT    70000
#define DIM_IN  768
#define HID     256
#define NHEAD   8
#define CH      256
#define HC      2048
#define NLAYER  4
#define NCLS    2
#define EPSLN   1e-5f
#define SLOPE   0.2f
#define DEG_CAP 128

typedef __bf16 bf16;
typedef __bf16 bf16x8 __attribute__((ext_vector_type(8)));
typedef float  f32x4  __attribute__((ext_vector_type(4)));

__device__ __forceinline__ float gelu_erf(float x) {
  return 0.5f * x * (1.0f + erff(x * 0.70710678118654752f));
}

// async global->LDS, 16B per lane
__device__ __forceinline__ void gl2lds16(const void* g, void* l) {
  __builtin_amdgcn_global_load_lds(
      (const __attribute__((address_space(1))) unsigned int*)g,
      (__attribute__((address_space(3))) unsigned int*)l,
      16, 0, 0);
}

// ---------------- CSR build ----------------
__global__ void k_count(const int* __restrict__ ei, int* __restrict__ deg) {
  int e = blockIdx.x * 256 + threadIdx.x;
  if (e >= ETOT) return;
  int d = (e < N_EDGES) ? ei[N_EDGES + e] : (e - N_EDGES);
  atomicAdd(&deg[d], 1);
}

__global__ void k_scan(const int* __restrict__ deg, int* __restrict__ offs) {
  __shared__ int lds[1024];
  const int t = threadIdx.x;
  const int c0 = t * 10;
  int s = 0;
  #pragma unroll
  for (int q = 0; q < 10; ++q) { int idx = c0 + q; if (idx < N_NODES) s += deg[idx]; }
  lds[t] = s;
  __syncthreads();
  for (int o = 1; o < 1024; o <<= 1) {
    int v = (t >= o) ? lds[t - o] : 0;
    __syncthreads();
    lds[t] += v;
    __syncthreads();
  }
  int run = lds[t] - s;
  #pragma unroll
  for (int q = 0; q < 10; ++q) {
    int idx = c0 + q;
    if (idx < N_NODES) { offs[idx] = run; run += deg[idx]; }
  }
  if (t == 1023) offs[N_NODES] = lds[1023];
}

__global__ void k_scatter(const int* __restrict__ ei, const int* __restrict__ offs,
                          int* __restrict__ fill, int* __restrict__ adj) {
  int e = blockIdx.x * 256 + threadIdx.x;
  if (e >= ETOT) return;
  int s, d;
  if (e < N_EDGES) { s = ei[e]; d = ei[N_EDGES + e]; } else { s = e - N_EDGES; d = s; }
  int pos = offs[d] + atomicAdd(&fill[d], 1);
  adj[pos] = s;
}

__global__ void k_init_vn(const float* __restrict__ vnode, float* __restrict__ vn_cur) {
  int t = threadIdx.x;
  if (t < HID) vn_cur[t] = vnode[t];
}

// ---------------- f32 -> bf16 convert (grid-stride, 4-wide) ----------------
__global__ void k_f2b(const float* __restrict__ src, bf16* __restrict__ dst, int n4) {
  int i = blockIdx.x * 256 + threadIdx.x;
  int stride = gridDim.x * 256;
  for (; i < n4; i += stride) {
    float4 v = reinterpret_cast<const float4*>(src)[i];
    bf16 o0 = (bf16)v.x, o1 = (bf16)v.y, o2 = (bf16)v.z, o3 = (bf16)v.w;
    ushort4 pack;
    pack.x = __builtin_bit_cast(unsigned short, o0);
    pack.y = __builtin_bit_cast(unsigned short, o1);
    pack.z = __builtin_bit_cast(unsigned short, o2);
    pack.w = __builtin_bit_cast(unsigned short, o3);
    reinterpret_cast<ushort4*>(dst)[i] = pack;
  }
}

// ---------------- concat [Wl;Wr] -> bf16 [NLAYER][4096][256] ----------------
__global__ void k_catw(const float* __restrict__ Wl, const float* __restrict__ Wr,
                       bf16* __restrict__ out) {
  int idx = blockIdx.x * 256 + threadIdx.x;        // one per 8 elements
  const int total8 = NLAYER * 4096 * 256 / 8;
  if (idx >= total8) return;
  size_t flat = (size_t)idx * 8;
  int i   = (int)(flat / (4096 * 256));
  int rem = (int)(flat % (4096 * 256));
  int r = rem >> 8;
  int k = rem & 255;
  const float* src = (r < 2048)
      ? Wl + (((size_t)i * 2048 + r) << 8) + k
      : Wr + (((size_t)i * 2048 + (r - 2048)) << 8) + k;
  const float4* p4 = reinterpret_cast<const float4*>(src);
  float4 u0 = p4[0], u1 = p4[1];
  bf16x8 ov;
  ov[0]=(bf16)u0.x; ov[1]=(bf16)u0.y; ov[2]=(bf16)u0.z; ov[3]=(bf16)u0.w;
  ov[4]=(bf16)u1.x; ov[5]=(bf16)u1.y; ov[6]=(bf16)u1.z; ov[7]=(bf16)u1.w;
  reinterpret_cast<bf16x8*>(out)[idx] = ov;
}

__global__ void k_catb(const float* __restrict__ bl, const float* __restrict__ br,
                       float* __restrict__ out) {
  int idx = blockIdx.x * 256 + threadIdx.x;        // NLAYER*4096
  if (idx >= NLAYER * 4096) return;
  int i = idx >> 12, r = idx & 4095;
  out[idx] = (r < 2048) ? bl[i * 2048 + r] : br[i * 2048 + (r - 2048)];
}

// ---------------- bf16 MFMA GEMM: 128x128 tile, BK=32, counted-vmcnt dbuf pipeline --------
// LDS 32KB -> 5 blocks/CU. 1D grid, m204 bijective XCD swizzle, N-fastest tile order.
// C[M,N] = act(A[M,K] @ W[N,K]^T + bias). A rows padded to M_PAD (no staging guard).
template<int ACT, bool WB, bool WF>
__global__ __launch_bounds__(256) void k_gemm2(
    const bf16* __restrict__ A, int lda,
    const bf16* __restrict__ W, int ldw,
    const float* __restrict__ bias,
    bf16* __restrict__ Cb, float* __restrict__ Cf, int ldc,
    int M, int K, int NT)
{
  __shared__ bf16 As[2][128 * 32];
  __shared__ bf16 Bs[2][128 * 32];
  const int t = threadIdx.x;
  const int nwg = gridDim.x;
  const int qq = nwg >> 3, rr = nwg & 7;
  const int xcd = blockIdx.x & 7, loc = blockIdx.x >> 3;
  const int wg = (xcd < rr) ? (xcd * (qq + 1) + loc)
                            : (rr * (qq + 1) + (xcd - rr) * qq + loc);
  const int bm = (wg / NT) * 128;
  const int bn = (wg % NT) * 128;
  const int l = t & 63, w = t >> 6;
  const int wm = (w >> 1) * 64, wn = (w & 1) * 64;
  const int lr = l & 15, lg = l >> 4;
  const int sr = t >> 2;     // staging row 0..63
  const int ps = t & 3;      // physical 16B slot within 64B row

  f32x4 acc[4][4];
  #pragma unroll
  for (int a = 0; a < 4; ++a)
    #pragma unroll
    for (int b = 0; b < 4; ++b) acc[a][b] = (f32x4){0.f, 0.f, 0.f, 0.f};

  auto stage = [&](int buf, int k0) {
    #pragma unroll
    for (int q = 0; q < 2; ++q) {
      int r = q * 64 + sr;
      int ls = ps ^ ((r >> 1) & 3);                // inverse-swizzled source slot
      gl2lds16(A + (size_t)(bm + r) * lda + k0 + ls * 8, &As[buf][r * 32 + ps * 8]);
    }
    #pragma unroll
    for (int q = 0; q < 2; ++q) {
      int r = q * 64 + sr;
      int ls = ps ^ ((r >> 1) & 3);
      gl2lds16(W + (size_t)(bn + r) * ldw + k0 + ls * 8, &Bs[buf][r * 32 + ps * 8]);
    }
  };

  const int nt = K >> 5;
  stage(0, 0);                                     // 4 loads in flight
  for (int kt = 0; kt < nt; ++kt) {
    if (kt + 1 < nt) {
      stage((kt + 1) & 1, (kt + 1) << 5);          // +4 -> 8 in flight
      asm volatile("s_waitcnt vmcnt(4)" ::: "memory");  // wait cur's 4; prefetch stays
    } else {
      asm volatile("s_waitcnt vmcnt(0)" ::: "memory");
    }
    __builtin_amdgcn_s_barrier();                  // cur buf ready across waves
    asm volatile("" ::: "memory");
    const bf16* Ab = As[kt & 1];
    const bf16* Bb = Bs[kt & 1];
    bf16x8 af[4], bfr[4];
    #pragma unroll
    for (int mt = 0; mt < 4; ++mt) {
      int row = wm + mt * 16 + lr;
      af[mt] = *reinterpret_cast<const bf16x8*>(&Ab[row * 32 + ((lg ^ ((row >> 1) & 3)) * 8)]);
    }
    #pragma unroll
    for (int nt2 = 0; nt2 < 4; ++nt2) {
      int row = wn + nt2 * 16 + lr;
      bfr[nt2] = *reinterpret_cast<const bf16x8*>(&Bb[row * 32 + ((lg ^ ((row >> 1) & 3)) * 8)]);
    }
    #pragma unroll
    for (int mt = 0; mt < 4; ++mt)
      #pragma unroll
      for (int nt2 = 0; nt2 < 4; ++nt2)
        acc[mt][nt2] = __builtin_amdgcn_mfma_f32_16x16x32_bf16(af[mt], bfr[nt2], acc[mt][nt2], 0, 0, 0);
    asm volatile("" ::: "memory");
    __builtin_amdgcn_s_barrier();                  // all reads done before next overwrite
    asm volatile("" ::: "memory");
  }
  #pragma unroll
  for (int mt = 0; mt < 4; ++mt) {
    #pragma unroll
    for (int nt2 = 0; nt2 < 4; ++nt2) {
      int col = bn + wn + nt2 * 16 + lr;
      float bv = bias[col];
      #pragma unroll
      for (int j = 0; j < 4; ++j) {
        int row = bm + wm + mt * 16 + lg * 4 + j;
        if (row < M) {
          float vv = acc[mt][nt2][j] + bv;
          if (ACT == 1) vv = gelu_erf(vv);
          if (WB) Cb[(size_t)row * ldc + col] = (bf16)vv;
          if (WF) Cf[(size_t)row * ldc + col] = vv;
        }
      }
    }
  }
}

// ---------------- fused GATv2 attention (online softmax, defer-max) + mean + res + LN ----
// leaky(z) with slope 0.2 == 0.6z + 0.4|z| exactly -> fold into dot with pre-scaled att.
__global__ __launch_bounds__(256) void k_node_attn(
    float* __restrict__ x, bf16* __restrict__ xb,
    const bf16* __restrict__ xlr,   // [M_PAD][4096]: xl cols 0..2047, xr cols 2048..4095
    const int* __restrict__ offs, const int* __restrict__ adj,
    const float* __restrict__ att_l, const float* __restrict__ gbias_l,
    const float* __restrict__ g_l, const float* __restrict__ b_l)
{
  __shared__ int   s_src[DEG_CAP];
  __shared__ float s_agg[HC];
  __shared__ float s_red[8];

  const int t = threadIdx.x;
  const int i = blockIdx.x;
  const int start = offs[i];
  int deg = offs[i + 1] - start;
  if (deg > DEG_CAP) deg = DEG_CAP;

  for (int j = t; j < deg; j += 256) s_src[j] = adj[start + j];

  float xr_reg[8], a6[8], a4[8];
  {
    bf16x8 xv = *reinterpret_cast<const bf16x8*>(xlr + (size_t)i * 4096 + 2048 + 8 * t);
    #pragma unroll
    for (int q = 0; q < 8; ++q) xr_reg[q] = (float)xv[q];
    const float4* ap = reinterpret_cast<const float4*>(att_l + 8 * t);
    float4 a0 = ap[0], a1 = ap[1];
    a6[0]=0.6f*a0.x; a6[1]=0.6f*a0.y; a6[2]=0.6f*a0.z; a6[3]=0.6f*a0.w;
    a6[4]=0.6f*a1.x; a6[5]=0.6f*a1.y; a6[6]=0.6f*a1.z; a6[7]=0.6f*a1.w;
    a4[0]=0.4f*a0.x; a4[1]=0.4f*a0.y; a4[2]=0.4f*a0.z; a4[3]=0.4f*a0.w;
    a4[4]=0.4f*a1.x; a4[5]=0.4f*a1.y; a4[6]=0.4f*a1.z; a4[7]=0.4f*a1.w;
  }
  __syncthreads();

  // online softmax with defer-max rescale
  float m = -1e30f, ssum = 0.f;
  float acc[8];
  #pragma unroll
  for (int q = 0; q < 8; ++q) acc[q] = 0.f;

  for (int j = 0; j < deg; ++j) {
    bf16x8 xv = *reinterpret_cast<const bf16x8*>(xlr + (size_t)s_src[j] * 4096 + 8 * t);
    float xf[8];
    float p = 0.f;
    #pragma unroll
    for (int q = 0; q < 8; ++q) {
      xf[q] = (float)xv[q];
      float z = xf[q] + xr_reg[q];
      p = fmaf(a6[q], z, p);
      p = fmaf(a4[q], fabsf(z), p);   // |z| is a free src modifier
    }
    #pragma unroll
    for (int o = 16; o >= 1; o >>= 1) p += __shfl_xor(p, o, 32);
    if (__any(p > m)) {                 // rescale only when some head's max grows
      float mn = fmaxf(m, p);
      float scale = __expf(m - mn);     // ==1 for heads whose max didn't grow
      ssum *= scale;
      #pragma unroll
      for (int q = 0; q < 8; ++q) acc[q] *= scale;
      m = mn;
    }
    float a = __expf(p - m);
    ssum += a;
    #pragma unroll
    for (int q = 0; q < 8; ++q) acc[q] = fmaf(a, xf[q], acc[q]);
  }
  float inv = 1.0f / ssum;
  #pragma unroll
  for (int q = 0; q < 8; ++q) s_agg[8 * t + q] = acc[q] * inv;
  __syncthreads();

  float xloc = 0.f;
  #pragma unroll
  for (int hh = 0; hh < NHEAD; ++hh) xloc += s_agg[hh * CH + t];
  xloc = xloc * (1.0f / NHEAD) + gbias_l[t];
  float r = x[(size_t)i * HID + t] + xloc;

  float s1 = r, s2 = r * r;
  #pragma unroll
  for (int o = 32; o >= 1; o >>= 1) { s1 += __shfl_xor(s1, o); s2 += __shfl_xor(s2, o); }
  if ((t & 63) == 0) { s_red[t >> 6] = s1; s_red[4 + (t >> 6)] = s2; }
  __syncthreads();
  s1 = s_red[0] + s_red[1] + s_red[2] + s_red[3];
  s2 = s_red[4] + s_red[5] + s_red[6] + s_red[7];
  float mean = s1 * (1.0f / HID);
  float var  = s2 * (1.0f / HID) - mean * mean;
  float o = (r - mean) * rsqrtf(var + EPSLN) * g_l[t] + b_l[t];
  x [(size_t)i * HID + t] = o;
  xb[(size_t)i * HID + t] = (bf16)o;
}

// ---------------- column mean partials ----------------
__global__ void k_colmean(const float* __restrict__ x, float* __restrict__ accum) {
  const int t = threadIdx.x, b = blockIdx.x;
  float s = 0.f;
  for (int r = b * 50; r < (b + 1) * 50; ++r) s += x[(size_t)r * HID + t];
  atomicAdd(&accum[t], s);
}

// ---------------- vn path: multi-block GEMVs + tiny LN ----------------
__global__ void k_vn_gemv1(const float* __restrict__ vn_accum,
                           const float* __restrict__ V1, const float* __restrict__ v1b,
                           float* __restrict__ z1) {
  const int o = blockIdx.x * 8 + (threadIdx.x >> 5);
  const int lane = threadIdx.x & 31;
  const float4* vp = reinterpret_cast<const float4*>(vn_accum + lane * 8);
  float4 a0 = vp[0], a1 = vp[1];
  const float4* wp = reinterpret_cast<const float4*>(V1 + (size_t)o * 256 + lane * 8);
  float4 w0 = wp[0], w1 = wp[1];
  float p = a0.x*w0.x + a0.y*w0.y + a0.z*w0.z + a0.w*w0.w
          + a1.x*w1.x + a1.y*w1.y + a1.z*w1.z + a1.w*w1.w;
  #pragma unroll
  for (int s = 16; s >= 1; s >>= 1) p += __shfl_xor(p, s, 32);
  if (lane == 0) z1[o] = gelu_erf(p * (1.0f / (float)N_NODES) + v1b[o]);
}

__global__ void k_vn_gemv2(const float* __restrict__ z1,
                           const float* __restrict__ V2, const float* __restrict__ v2b,
                           float* __restrict__ vn_up) {
  const int o = blockIdx.x * 8 + (threadIdx.x >> 5);
  const int lane = threadIdx.x & 31;
  float p = 0.f;
  #pragma unroll
  for (int c = 0; c < 4; ++c) {
    float4 a = reinterpret_cast<const float4*>(z1 + lane * 16)[c];
    float4 w = reinterpret_cast<const float4*>(V2 + (size_t)o * 512 + lane * 16)[c];
    p += a.x*w.x + a.y*w.y + a.z*w.z + a.w*w.w;
  }
  #pragma unroll
  for (int s = 16; s >= 1; s >>= 1) p += __shfl_xor(p, s, 32);
  if (lane == 0) vn_up[o] = p + v2b[o];
}

__global__ void k_vn_ln(float* __restrict__ vn_cur, const float* __restrict__ vn_up,
                        const float* __restrict__ g2, const float* __restrict__ be2) {
  __shared__ float s_red[8];
  const int t = threadIdx.x;
  float r = vn_cur[t] + vn_up[t];
  float s1 = r, s2 = r * r;
  #pragma unroll
  for (int o = 32; o >= 1; o >>= 1) { s1 += __shfl_xor(s1, o); s2 += __shfl_xor(s2, o); }
  if ((t & 63) == 0) { s_red[t >> 6] = s1; s_red[4 + (t >> 6)] = s2; }
  __syncthreads();
  s1 = s_red[0] + s_red[1] + s_red[2] + s_red[3];
  s2 = s_red[4] + s_red[5] + s_red[6] + s_red[7];
  float mean = s1 * (1.0f / HID);
  float var  = s2 * (1.0f / HID) - mean * mean;
  vn_cur[t] = (r - mean) * rsqrtf(var + EPSLN) * g2[t] + be2[t];
}

__global__ void k_vn_ctr(const float* __restrict__ vn_cur,
                         const float* __restrict__ U1, const float* __restrict__ u1b,
                         float* __restrict__ vn_ctr) {
  const int o = blockIdx.x * 8 + (threadIdx.x >> 5);
  const int lane = threadIdx.x & 31;
  const float4* vp = reinterpret_cast<const float4*>(vn_cur + lane * 8);
  float4 a0 = vp[0], a1 = vp[1];
  const float4* wp = reinterpret_cast<const float4*>(U1 + (size_t)o * 512 + 256 + lane * 8);
  float4 w0 = wp[0], w1 = wp[1];
  float p = a0.x*w0.x + a0.y*w0.y + a0.z*w0.z + a0.w*w0.w
          + a1.x*w1.x + a1.y*w1.y + a1.z*w1.z + a1.w*w1.w;
  #pragma unroll
  for (int s = 16; s >= 1; s >>= 1) p += __shfl_xor(p, s, 32);
  if (lane == 0) vn_ctr[o] = p + u1b[o];
}

// ---------------- residual + LN ----------------
__global__ __launch_bounds__(256) void k_ln_res(
    float* __restrict__ x, bf16* __restrict__ xb, const float* __restrict__ xu,
    const float* __restrict__ g_l, const float* __restrict__ b_l)
{
  __shared__ float s_red[8];
  const int t = threadIdx.x, i = blockIdx.x;
  float r = x[(size_t)i * HID + t] + xu[(size_t)i * HID + t];
  float s1 = r, s2 = r * r;
  #pragma unroll
  for (int o = 32; o >= 1; o >>= 1) { s1 += __shfl_xor(s1, o); s2 += __shfl_xor(s2, o); }
  if ((t & 63) == 0) { s_red[t >> 6] = s1; s_red[4 + (t >> 6)] = s2; }
  __syncthreads();
  s1 = s_red[0] + s_red[1] + s_red[2] + s_red[3];
  s2 = s_red[4] + s_red[5] + s_red[6] + s_red[7];
  float mean = s1 * (1.0f / HID);
  float var  = s2 * (1.0f / HID) - mean * mean;
  float o = (r - mean) * rsqrtf(var + EPSLN) * g_l[t] + b_l[t];
  x [(size_t)i * HID + t] = o;
  xb[(size_t)i * HID + t] = (bf16)o;
}

// ---------------- final tiny head ----------------
__global__ void k_final(const float* __restrict__ g, const float* __restrict__ O2,
                        const float* __restrict__ o2b, float* __restrict__ out) {
  int tid = blockIdx.x * 256 + threadIdx.x;
  if (tid >= N_NODES * NCLS) return;
  int n = tid >> 1, j = tid & 1;
  const float* gr = g + (size_t)n * HID;
  const float* w  = O2 + (size_t)j * HID;
  float d = o2b[j];
  for (int k = 0; k < HID; ++k) d = fmaf(gr[k], w[k], d);
  out[tid] = d;
}

extern "C" void kernel_launch(void* const* d_in, const int* in_sizes, int n_in,
                              void* d_out, int out_size, void* d_ws, size_t ws_size,
                              hipStream_t stream)
{
  const float* x_in  = (const float*)d_in[0];
  const int*   ei    = (const int*)  d_in[1];
  const float* W_in  = (const float*)d_in[2];
  const float* b_in  = (const float*)d_in[3];
  const float* vnode = (const float*)d_in[4];
  const float* Wl    = (const float*)d_in[5];
  const float* bl    = (const float*)d_in[6];
  const float* Wr    = (const float*)d_in[7];
  const float* br    = (const float*)d_in[8];
  const float* att   = (const float*)d_in[9];
  const float* gbias = (const float*)d_in[10];
  const float* V1    = (const float*)d_in[11];
  const float* v1b   = (const float*)d_in[12];
  const float* V2    = (const float*)d_in[13];
  const float* v2b   = (const float*)d_in[14];
  const float* U1    = (const float*)d_in[15];
  const float* u1b   = (const float*)d_in[16];
  const float* U2    = (const float*)d_in[17];
  const float* u2b   = (const float*)d_in[18];
  const float* g1    = (const float*)d_in[19];
  const float* be1   = (const float*)d_in[20];
  const float* g2    = (const float*)d_in[21];
  const float* be2   = (const float*)d_in[22];
  const float* g3    = (const float*)d_in[23];
  const float* be3   = (const float*)d_in[24];
  const float* O1    = (const float*)d_in[25];
  const float* o1b   = (const float*)d_in[26];
  const float* O2    = (const float*)d_in[27];
  const float* o2b   = (const float*)d_in[28];
  float* out = (float*)d_out;

  char* ws = (char*)d_ws;
  size_t cur = 0;
  auto alloc = [&](size_t bytes) -> char* {
    char* p = ws + cur;
    cur = (cur + bytes + 255) & ~(size_t)255;
    return p;
  };
  float* x        = (float*)alloc((size_t)M_PAD * HID * 4);
  bf16*  xb       = (bf16*) alloc((size_t)M_PAD * HID * 2);
  bf16*  xlr      = (bf16*) alloc((size_t)M_PAD * 4096 * 2);
  bf16*  h1       = (bf16*) alloc((size_t)M_PAD * 2 * HID * 2);
  float* xu       = (float*)alloc((size_t)M_PAD * HID * 4);
  bf16*  Wlrb     = (bf16*) alloc((size_t)NLAYER * 4096 * HID * 2);
  float* blr      = (float*)alloc((size_t)NLAYER * 4096 * 4);
  bf16*  U1b      = (bf16*) alloc((size_t)NLAYER * 2 * HID * 2 * HID * 2);
  bf16*  U2b      = (bf16*) alloc((size_t)NLAYER * HID * 2 * HID * 2);
  bf16*  O1b      = (bf16*) alloc((size_t)HID * HID * 2);
  bf16*  Winb     = (bf16*) alloc((size_t)HID * DIM_IN * 2);
  int*   deg      = (int*)  alloc((size_t)N_NODES * 4);
  int*   offs     = (int*)  alloc((size_t)(N_NODES + 1) * 4);
  int*   fill     = (int*)  alloc((size_t)N_NODES * 4);
  int*   adj      = (int*)  alloc((size_t)ETOT * 4);
  float* vn_accum = (float*)alloc(HID * 4);
  float* vn_cur   = (float*)alloc(HID * 4);
  float* vn_ctr   = (float*)alloc(2 * HID * 4);
  float* z1buf    = (float*)alloc(2 * HID * 4);
  float* vn_up    = (float*)alloc(HID * 4);

  // x_in as padded bf16 reuses xlr space (xlr unused until first layer GEMM)
  bf16* x_in_b = xlr;

  // CSR build
  hipMemsetAsync(deg, 0, (size_t)N_NODES * 4, stream);
  hipMemsetAsync(fill, 0, (size_t)N_NODES * 4, stream);
  k_count<<<(ETOT + 255) / 256, 256, 0, stream>>>(ei, deg);
  k_scan<<<1, 1024, 0, stream>>>(deg, offs);
  k_scatter<<<(ETOT + 255) / 256, 256, 0, stream>>>(ei, offs, fill, adj);
  k_init_vn<<<1, 256, 0, stream>>>(vnode, vn_cur);

  // weight prep
  k_catw<<<(NLAYER * 4096 * 256 / 8 + 255) / 256, 256, 0, stream>>>(Wl, Wr, Wlrb);
  k_catb<<<(NLAYER * 4096 + 255) / 256, 256, 0, stream>>>(bl, br, blr);
  k_f2b<<<256, 256, 0, stream>>>(U1, U1b, NLAYER * 2 * HID * 2 * HID / 4);
  k_f2b<<<128, 256, 0, stream>>>(U2, U2b, NLAYER * HID * 2 * HID / 4);
  k_f2b<<<64, 256, 0, stream>>>(O1, O1b, HID * HID / 4);
  k_f2b<<<64, 256, 0, stream>>>(W_in, Winb, HID * DIM_IN / 4);
  k_f2b<<<512, 256, 0, stream>>>(x_in, x_in_b, N_NODES * DIM_IN / 4);

  const int MT = M_PAD / 128;   // 79

  // input projection: x (fp32) + xb (bf16) in one GEMM
  k_gemm2<0, true, true><<<MT * 2, 256, 0, stream>>>(
      x_in_b, DIM_IN, Winb, DIM_IN, b_in, xb, x, HID, N_NODES, DIM_IN, 2);

  for (int i = 0; i < NLAYER; ++i) {
    const bf16* Wlrb_i = Wlrb + (size_t)i * 4096 * HID;
    const bf16* U1b_i  = U1b + (size_t)i * 2 * HID * 2 * HID;
    const bf16* U2b_i  = U2b + (size_t)i * HID * 2 * HID;

    // xlr = x @ [Wl;Wr]^T + [bl;br]   (single combined GEMM, 2528 blocks)
    k_gemm2<0, true, false><<<MT * 32, 256, 0, stream>>>(
        xb, HID, Wlrb_i, HID, blr + (size_t)i * 4096, xlr, nullptr, 4096, N_NODES, HID, 32);

    k_node_attn<<<N_NODES, 256, 0, stream>>>(x, xb, xlr, offs, adj,
        att + (size_t)i * HC, gbias + (size_t)i * HID,
        g1 + (size_t)i * HID, be1 + (size_t)i * HID);

    hipMemsetAsync(vn_accum, 0, HID * 4, stream);
    k_colmean<<<200, 256, 0, stream>>>(x, vn_accum);
    k_vn_gemv1<<<64, 256, 0, stream>>>(vn_accum,
        V1 + (size_t)i * 2 * HID * HID, v1b + (size_t)i * 2 * HID, z1buf);
    k_vn_gemv2<<<32, 256, 0, stream>>>(z1buf,
        V2 + (size_t)i * HID * 2 * HID, v2b + (size_t)i * HID, vn_up);
    k_vn_ln<<<1, 256, 0, stream>>>(vn_cur, vn_up,
        g2 + (size_t)i * HID, be2 + (size_t)i * HID);
    k_vn_ctr<<<64, 256, 0, stream>>>(vn_cur,
        U1 + (size_t)i * 2 * HID * 2 * HID, u1b + (size_t)i * 2 * HID, vn_ctr);

    // h1 = gelu(x @ U1[:, :256]^T + vn_ctr)  (bf16 out)
    k_gemm2<1, true, false><<<MT * 4, 256, 0, stream>>>(
        xb, HID, U1b_i, 2 * HID, vn_ctr, h1, nullptr, 2 * HID, N_NODES, HID, 4);
    // xu = h1 @ U2^T + u2b  (fp32 out)
    k_gemm2<0, false, true><<<MT * 2, 256, 0, stream>>>(
        h1, 2 * HID, U2b_i, 2 * HID, u2b + (size_t)i * HID, nullptr, xu, HID, N_NODES, 2 * HID, 2);

    k_ln_res<<<N_NODES, 256, 0, stream>>>(x, xb, xu, g3 + (size_t)i * HID, be3 + (size_t)i * HID);
  }

  // final head: gelu(x @ O1^T + o1b) -> xu (fp32), then tiny N=2 matvec
  k_gemm2<1, false, true><<<MT * 2, 256, 0, stream>>>(
      xb, HID, O1b, HID, o1b, nullptr, xu, HID, N_NODES, HID, 2);
  k_final<<<(N_NODES * NCLS + 255) / 256, 256, 0, stream>>>(xu, O2, o2b, out);
}

// Round 10
// 968.362 us; speedup vs baseline: 1.0527x; 1.0527x over previous
//
#include <hip/hip_runtime.h>
#include <hip/hip_bf16.h>
#include <cstdint>
#include <cstddef>

#define N_NODES 10000
#define M_PAD   10112   // N_NODES rounded up to 128
#define N_EDGES 60000
#define ETOT    70000
#define DIM_IN  768
#define HID     256
#define NHEAD   8
#define CH      256
#define HC      2048
#define NLAYER  4
#define NCLS    2
#define EPSLN   1e-5f
#define SLOPE   0.2f
#define DEG_CAP 128

typedef __bf16 bf16;
typedef __bf16 bf16x8 __attribute__((ext_vector_type(8)));
typedef float  f32x4  __attribute__((ext_vector_type(4)));

__device__ __forceinline__ float gelu_erf(float x) {
  return 0.5f * x * (1.0f + erff(x * 0.70710678118654752f));
}

// async global->LDS, 16B per lane
__device__ __forceinline__ void gl2lds16(const void* g, void* l) {
  __builtin_amdgcn_global_load_lds(
      (const __attribute__((address_space(1))) unsigned int*)g,
      (__attribute__((address_space(3))) unsigned int*)l,
      16, 0, 0);
}

// ---------------- CSR build ----------------
__global__ void k_count(const int* __restrict__ ei, int* __restrict__ deg) {
  int e = blockIdx.x * 256 + threadIdx.x;
  if (e >= ETOT) return;
  int d = (e < N_EDGES) ? ei[N_EDGES + e] : (e - N_EDGES);
  atomicAdd(&deg[d], 1);
}

__global__ void k_scan(const int* __restrict__ deg, int* __restrict__ offs) {
  __shared__ int lds[1024];
  const int t = threadIdx.x;
  const int c0 = t * 10;
  int s = 0;
  #pragma unroll
  for (int q = 0; q < 10; ++q) { int idx = c0 + q; if (idx < N_NODES) s += deg[idx]; }
  lds[t] = s;
  __syncthreads();
  for (int o = 1; o < 1024; o <<= 1) {
    int v = (t >= o) ? lds[t - o] : 0;
    __syncthreads();
    lds[t] += v;
    __syncthreads();
  }
  int run = lds[t] - s;
  #pragma unroll
  for (int q = 0; q < 10; ++q) {
    int idx = c0 + q;
    if (idx < N_NODES) { offs[idx] = run; run += deg[idx]; }
  }
  if (t == 1023) offs[N_NODES] = lds[1023];
}

__global__ void k_scatter(const int* __restrict__ ei, const int* __restrict__ offs,
                          int* __restrict__ fill, int* __restrict__ adj) {
  int e = blockIdx.x * 256 + threadIdx.x;
  if (e >= ETOT) return;
  int s, d;
  if (e < N_EDGES) { s = ei[e]; d = ei[N_EDGES + e]; } else { s = e - N_EDGES; d = s; }
  int pos = offs[d] + atomicAdd(&fill[d], 1);
  adj[pos] = s;
}

__global__ void k_init_vn(const float* __restrict__ vnode, float* __restrict__ vn_cur) {
  int t = threadIdx.x;
  if (t < HID) vn_cur[t] = vnode[t];
}

// ---------------- f32 -> bf16 convert (grid-stride, 4-wide) ----------------
__global__ void k_f2b(const float* __restrict__ src, bf16* __restrict__ dst, int n4) {
  int i = blockIdx.x * 256 + threadIdx.x;
  int stride = gridDim.x * 256;
  for (; i < n4; i += stride) {
    float4 v = reinterpret_cast<const float4*>(src)[i];
    bf16 o0 = (bf16)v.x, o1 = (bf16)v.y, o2 = (bf16)v.z, o3 = (bf16)v.w;
    ushort4 pack;
    pack.x = __builtin_bit_cast(unsigned short, o0);
    pack.y = __builtin_bit_cast(unsigned short, o1);
    pack.z = __builtin_bit_cast(unsigned short, o2);
    pack.w = __builtin_bit_cast(unsigned short, o3);
    reinterpret_cast<ushort4*>(dst)[i] = pack;
  }
}

// ---------------- concat [Wl;Wr] -> bf16 [NLAYER][4096][256] ----------------
__global__ void k_catw(const float* __restrict__ Wl, const float* __restrict__ Wr,
                       bf16* __restrict__ out) {
  int idx = blockIdx.x * 256 + threadIdx.x;        // one per 8 elements
  const int total8 = NLAYER * 4096 * 256 / 8;
  if (idx >= total8) return;
  size_t flat = (size_t)idx * 8;
  int i   = (int)(flat / (4096 * 256));
  int rem = (int)(flat % (4096 * 256));
  int r = rem >> 8;
  int k = rem & 255;
  const float* src = (r < 2048)
      ? Wl + (((size_t)i * 2048 + r) << 8) + k
      : Wr + (((size_t)i * 2048 + (r - 2048)) << 8) + k;
  const float4* p4 = reinterpret_cast<const float4*>(src);
  float4 u0 = p4[0], u1 = p4[1];
  bf16x8 ov;
  ov[0]=(bf16)u0.x; ov[1]=(bf16)u0.y; ov[2]=(bf16)u0.z; ov[3]=(bf16)u0.w;
  ov[4]=(bf16)u1.x; ov[5]=(bf16)u1.y; ov[6]=(bf16)u1.z; ov[7]=(bf16)u1.w;
  reinterpret_cast<bf16x8*>(out)[idx] = ov;
}

__global__ void k_catb(const float* __restrict__ bl, const float* __restrict__ br,
                       float* __restrict__ out) {
  int idx = blockIdx.x * 256 + threadIdx.x;        // NLAYER*4096
  if (idx >= NLAYER * 4096) return;
  int i = idx >> 12, r = idx & 4095;
  out[idx] = (r < 2048) ? bl[i * 2048 + r] : br[i * 2048 + (r - 2048)];
}

// ---------------- bf16 MFMA GEMM: 128x128 tile, BK=64, counted-vmcnt dbuf pipeline --------
// 1D grid, m204 bijective XCD swizzle, N-fastest. Prefetch stays in flight across barrier.
template<int ACT, bool WB, bool WF>
__global__ __launch_bounds__(256) void k_gemm2(
    const bf16* __restrict__ A, int lda,
    const bf16* __restrict__ W, int ldw,
    const float* __restrict__ bias,
    bf16* __restrict__ Cb, float* __restrict__ Cf, int ldc,
    int M, int K, int NT)
{
  __shared__ bf16 As[2][128 * 64];
  __shared__ bf16 Bs[2][128 * 64];
  const int t = threadIdx.x;
  const int nwg = gridDim.x;
  const int qq = nwg >> 3, rr = nwg & 7;
  const int xcd = blockIdx.x & 7, loc = blockIdx.x >> 3;
  const int wg = (xcd < rr) ? (xcd * (qq + 1) + loc)
                            : (rr * (qq + 1) + (xcd - rr) * qq + loc);
  const int bm = (wg / NT) * 128;
  const int bn = (wg % NT) * 128;
  const int l = t & 63, w = t >> 6;
  const int wm = (w >> 1) * 64, wn = (w & 1) * 64;
  const int lr = l & 15, lg = l >> 4;
  const int sr = t >> 3;     // staging row within 32-row group
  const int ps = t & 7;      // physical 16B slot

  f32x4 acc[4][4];
  #pragma unroll
  for (int a = 0; a < 4; ++a)
    #pragma unroll
    for (int b = 0; b < 4; ++b) acc[a][b] = (f32x4){0.f, 0.f, 0.f, 0.f};

  auto stage = [&](int buf, int k0) {
    #pragma unroll
    for (int q = 0; q < 4; ++q) {
      int r = q * 32 + sr;
      int ls = ps ^ (r & 7);                       // inverse-swizzled source slot
      gl2lds16(A + (size_t)(bm + r) * lda + k0 + ls * 8, &As[buf][r * 64 + ps * 8]);
    }
    #pragma unroll
    for (int q = 0; q < 4; ++q) {
      int r = q * 32 + sr;
      int ls = ps ^ (r & 7);
      gl2lds16(W + (size_t)(bn + r) * ldw + k0 + ls * 8, &Bs[buf][r * 64 + ps * 8]);
    }
  };

  const int nt = K >> 6;
  stage(0, 0);                                     // 8 loads in flight
  for (int kt = 0; kt < nt; ++kt) {
    if (kt + 1 < nt) {
      stage((kt + 1) & 1, (kt + 1) << 6);          // +8 -> 16 in flight
      asm volatile("s_waitcnt vmcnt(8)" ::: "memory");  // cur's 8 landed; prefetch pending
    } else {
      asm volatile("s_waitcnt vmcnt(0)" ::: "memory");
    }
    __builtin_amdgcn_s_barrier();                  // cur buf ready across waves
    asm volatile("" ::: "memory");
    const bf16* Ab = As[kt & 1];
    const bf16* Bb = Bs[kt & 1];
    #pragma unroll
    for (int ks = 0; ks < 2; ++ks) {
      bf16x8 af[4], bfr[4];
      #pragma unroll
      for (int mt = 0; mt < 4; ++mt) {
        int row = wm + mt * 16 + lr;
        int slot = ks * 4 + lg;
        af[mt] = *reinterpret_cast<const bf16x8*>(&Ab[row * 64 + ((slot ^ (row & 7)) * 8)]);
      }
      #pragma unroll
      for (int nt2 = 0; nt2 < 4; ++nt2) {
        int row = wn + nt2 * 16 + lr;
        int slot = ks * 4 + lg;
        bfr[nt2] = *reinterpret_cast<const bf16x8*>(&Bb[row * 64 + ((slot ^ (row & 7)) * 8)]);
      }
      #pragma unroll
      for (int mt = 0; mt < 4; ++mt)
        #pragma unroll
        for (int nt2 = 0; nt2 < 4; ++nt2)
          acc[mt][nt2] = __builtin_amdgcn_mfma_f32_16x16x32_bf16(af[mt], bfr[nt2], acc[mt][nt2], 0, 0, 0);
    }
    asm volatile("" ::: "memory");
    __builtin_amdgcn_s_barrier();                  // all reads done before next overwrite
    asm volatile("" ::: "memory");
  }
  #pragma unroll
  for (int mt = 0; mt < 4; ++mt) {
    #pragma unroll
    for (int nt2 = 0; nt2 < 4; ++nt2) {
      int col = bn + wn + nt2 * 16 + lr;
      float bv = bias[col];
      #pragma unroll
      for (int j = 0; j < 4; ++j) {
        int row = bm + wm + mt * 16 + lg * 4 + j;
        if (row < M) {
          float vv = acc[mt][nt2][j] + bv;
          if (ACT == 1) vv = gelu_erf(vv);
          if (WB) Cb[(size_t)row * ldc + col] = (bf16)vv;
          if (WF) Cf[(size_t)row * ldc + col] = vv;
        }
      }
    }
  }
}

// ---------------- bf16 MFMA GEMM: 64x64 tile for small-N GEMMs (4x grid, 32KB LDS) -------
template<int ACT, bool WB, bool WF>
__global__ __launch_bounds__(256) void k_gemm64(
    const bf16* __restrict__ A, int lda,
    const bf16* __restrict__ W, int ldw,
    const float* __restrict__ bias,
    bf16* __restrict__ Cb, float* __restrict__ Cf, int ldc,
    int M, int K, int NT)
{
  __shared__ bf16 As[2][64 * 64];
  __shared__ bf16 Bs[2][64 * 64];
  const int t = threadIdx.x;
  const int nwg = gridDim.x;
  const int qq = nwg >> 3, rr = nwg & 7;
  const int xcd = blockIdx.x & 7, loc = blockIdx.x >> 3;
  const int wg = (xcd < rr) ? (xcd * (qq + 1) + loc)
                            : (rr * (qq + 1) + (xcd - rr) * qq + loc);
  const int bm = (wg / NT) * 64;
  const int bn = (wg % NT) * 64;
  const int l = t & 63, w = t >> 6;
  const int wm = (w >> 1) * 32, wn = (w & 1) * 32;
  const int lr = l & 15, lg = l >> 4;
  const int sr = t >> 3;     // staging row within 32-row group
  const int ps = t & 7;      // physical 16B slot

  f32x4 acc[2][2];
  #pragma unroll
  for (int a = 0; a < 2; ++a)
    #pragma unroll
    for (int b = 0; b < 2; ++b) acc[a][b] = (f32x4){0.f, 0.f, 0.f, 0.f};

  auto stage = [&](int buf, int k0) {
    #pragma unroll
    for (int q = 0; q < 2; ++q) {
      int r = q * 32 + sr;
      int ls = ps ^ (r & 7);
      gl2lds16(A + (size_t)(bm + r) * lda + k0 + ls * 8, &As[buf][r * 64 + ps * 8]);
    }
    #pragma unroll
    for (int q = 0; q < 2; ++q) {
      int r = q * 32 + sr;
      int ls = ps ^ (r & 7);
      gl2lds16(W + (size_t)(bn + r) * ldw + k0 + ls * 8, &Bs[buf][r * 64 + ps * 8]);
    }
  };

  const int nt = K >> 6;
  stage(0, 0);                                     // 4 loads in flight
  for (int kt = 0; kt < nt; ++kt) {
    if (kt + 1 < nt) {
      stage((kt + 1) & 1, (kt + 1) << 6);          // +4 -> 8 in flight
      asm volatile("s_waitcnt vmcnt(4)" ::: "memory");
    } else {
      asm volatile("s_waitcnt vmcnt(0)" ::: "memory");
    }
    __builtin_amdgcn_s_barrier();
    asm volatile("" ::: "memory");
    const bf16* Ab = As[kt & 1];
    const bf16* Bb = Bs[kt & 1];
    #pragma unroll
    for (int ks = 0; ks < 2; ++ks) {
      bf16x8 af[2], bfr[2];
      #pragma unroll
      for (int mt = 0; mt < 2; ++mt) {
        int row = wm + mt * 16 + lr;
        int slot = ks * 4 + lg;
        af[mt] = *reinterpret_cast<const bf16x8*>(&Ab[row * 64 + ((slot ^ (row & 7)) * 8)]);
      }
      #pragma unroll
      for (int nt2 = 0; nt2 < 2; ++nt2) {
        int row = wn + nt2 * 16 + lr;
        int slot = ks * 4 + lg;
        bfr[nt2] = *reinterpret_cast<const bf16x8*>(&Bb[row * 64 + ((slot ^ (row & 7)) * 8)]);
      }
      #pragma unroll
      for (int mt = 0; mt < 2; ++mt)
        #pragma unroll
        for (int nt2 = 0; nt2 < 2; ++nt2)
          acc[mt][nt2] = __builtin_amdgcn_mfma_f32_16x16x32_bf16(af[mt], bfr[nt2], acc[mt][nt2], 0, 0, 0);
    }
    asm volatile("" ::: "memory");
    __builtin_amdgcn_s_barrier();
    asm volatile("" ::: "memory");
  }
  #pragma unroll
  for (int mt = 0; mt < 2; ++mt) {
    #pragma unroll
    for (int nt2 = 0; nt2 < 2; ++nt2) {
      int col = bn + wn + nt2 * 16 + lr;
      float bv = bias[col];
      #pragma unroll
      for (int j = 0; j < 4; ++j) {
        int row = bm + wm + mt * 16 + lg * 4 + j;
        if (row < M) {
          float vv = acc[mt][nt2][j] + bv;
          if (ACT == 1) vv = gelu_erf(vv);
          if (WB) Cb[(size_t)row * ldc + col] = (bf16)vv;
          if (WF) Cf[(size_t)row * ldc + col] = vv;
        }
      }
    }
  }
}

// ---------------- fused GATv2 attention (online softmax, defer-max) + mean + res + LN ----
// leaky(z) with slope 0.2 == 0.6z + 0.4|z| exactly -> fold into dot with pre-scaled att.
__global__ __launch_bounds__(256) void k_node_attn(
    float* __restrict__ x, bf16* __restrict__ xb,
    const bf16* __restrict__ xlr,   // [M_PAD][4096]: xl cols 0..2047, xr cols 2048..4095
    const int* __restrict__ offs, const int* __restrict__ adj,
    const float* __restrict__ att_l, const float* __restrict__ gbias_l,
    const float* __restrict__ g_l, const float* __restrict__ b_l)
{
  __shared__ int   s_src[DEG_CAP];
  __shared__ float s_agg[HC];
  __shared__ float s_red[8];

  const int t = threadIdx.x;
  const int i = blockIdx.x;
  const int start = offs[i];
  int deg = offs[i + 1] - start;
  if (deg > DEG_CAP) deg = DEG_CAP;

  for (int j = t; j < deg; j += 256) s_src[j] = adj[start + j];

  float xr_reg[8], a6[8], a4[8];
  {
    bf16x8 xv = *reinterpret_cast<const bf16x8*>(xlr + (size_t)i * 4096 + 2048 + 8 * t);
    #pragma unroll
    for (int q = 0; q < 8; ++q) xr_reg[q] = (float)xv[q];
    const float4* ap = reinterpret_cast<const float4*>(att_l + 8 * t);
    float4 a0 = ap[0], a1 = ap[1];
    a6[0]=0.6f*a0.x; a6[1]=0.6f*a0.y; a6[2]=0.6f*a0.z; a6[3]=0.6f*a0.w;
    a6[4]=0.6f*a1.x; a6[5]=0.6f*a1.y; a6[6]=0.6f*a1.z; a6[7]=0.6f*a1.w;
    a4[0]=0.4f*a0.x; a4[1]=0.4f*a0.y; a4[2]=0.4f*a0.z; a4[3]=0.4f*a0.w;
    a4[4]=0.4f*a1.x; a4[5]=0.4f*a1.y; a4[6]=0.4f*a1.z; a4[7]=0.4f*a1.w;
  }
  __syncthreads();

  // online softmax with defer-max rescale
  float m = -1e30f, ssum = 0.f;
  float acc[8];
  #pragma unroll
  for (int q = 0; q < 8; ++q) acc[q] = 0.f;

  for (int j = 0; j < deg; ++j) {
    bf16x8 xv = *reinterpret_cast<const bf16x8*>(xlr + (size_t)s_src[j] * 4096 + 8 * t);
    float xf[8];
    float p = 0.f;
    #pragma unroll
    for (int q = 0; q < 8; ++q) {
      xf[q] = (float)xv[q];
      float z = xf[q] + xr_reg[q];
      p = fmaf(a6[q], z, p);
      p = fmaf(a4[q], fabsf(z), p);   // |z| is a free src modifier
    }
    #pragma unroll
    for (int o = 16; o >= 1; o >>= 1) p += __shfl_xor(p, o, 32);
    if (__any(p > m)) {                 // rescale only when some head's max grows
      float mn = fmaxf(m, p);
      float scale = __expf(m - mn);     // ==1 for heads whose max didn't grow
      ssum *= scale;
      #pragma unroll
      for (int q = 0; q < 8; ++q) acc[q] *= scale;
      m = mn;
    }
    float a = __expf(p - m);
    ssum += a;
    #pragma unroll
    for (int q = 0; q < 8; ++q) acc[q] = fmaf(a, xf[q], acc[q]);
  }
  float inv = 1.0f / ssum;
  #pragma unroll
  for (int q = 0; q < 8; ++q) s_agg[8 * t + q] = acc[q] * inv;
  __syncthreads();

  float xloc = 0.f;
  #pragma unroll
  for (int hh = 0; hh < NHEAD; ++hh) xloc += s_agg[hh * CH + t];
  xloc = xloc * (1.0f / NHEAD) + gbias_l[t];
  float r = x[(size_t)i * HID + t] + xloc;

  float s1 = r, s2 = r * r;
  #pragma unroll
  for (int o = 32; o >= 1; o >>= 1) { s1 += __shfl_xor(s1, o); s2 += __shfl_xor(s2, o); }
  if ((t & 63) == 0) { s_red[t >> 6] = s1; s_red[4 + (t >> 6)] = s2; }
  __syncthreads();
  s1 = s_red[0] + s_red[1] + s_red[2] + s_red[3];
  s2 = s_red[4] + s_red[5] + s_red[6] + s_red[7];
  float mean = s1 * (1.0f / HID);
  float var  = s2 * (1.0f / HID) - mean * mean;
  float o = (r - mean) * rsqrtf(var + EPSLN) * g_l[t] + b_l[t];
  x [(size_t)i * HID + t] = o;
  xb[(size_t)i * HID + t] = (bf16)o;
}

// ---------------- column mean partials ----------------
__global__ void k_colmean(const float* __restrict__ x, float* __restrict__ accum) {
  const int t = threadIdx.x, b = blockIdx.x;
  float s = 0.f;
  for (int r = b * 50; r < (b + 1) * 50; ++r) s += x[(size_t)r * HID + t];
  atomicAdd(&accum[t], s);
}

// ---------------- vn path: multi-block GEMVs + tiny LN ----------------
__global__ void k_vn_gemv1(const float* __restrict__ vn_accum,
                           const float* __restrict__ V1, const float* __restrict__ v1b,
                           float* __restrict__ z1) {
  const int o = blockIdx.x * 8 + (threadIdx.x >> 5);
  const int lane = threadIdx.x & 31;
  const float4* vp = reinterpret_cast<const float4*>(vn_accum + lane * 8);
  float4 a0 = vp[0], a1 = vp[1];
  const float4* wp = reinterpret_cast<const float4*>(V1 + (size_t)o * 256 + lane * 8);
  float4 w0 = wp[0], w1 = wp[1];
  float p = a0.x*w0.x + a0.y*w0.y + a0.z*w0.z + a0.w*w0.w
          + a1.x*w1.x + a1.y*w1.y + a1.z*w1.z + a1.w*w1.w;
  #pragma unroll
  for (int s = 16; s >= 1; s >>= 1) p += __shfl_xor(p, s, 32);
  if (lane == 0) z1[o] = gelu_erf(p * (1.0f / (float)N_NODES) + v1b[o]);
}

__global__ void k_vn_gemv2(const float* __restrict__ z1,
                           const float* __restrict__ V2, const float* __restrict__ v2b,
                           float* __restrict__ vn_up) {
  const int o = blockIdx.x * 8 + (threadIdx.x >> 5);
  const int lane = threadIdx.x & 31;
  float p = 0.f;
  #pragma unroll
  for (int c = 0; c < 4; ++c) {
    float4 a = reinterpret_cast<const float4*>(z1 + lane * 16)[c];
    float4 w = reinterpret_cast<const float4*>(V2 + (size_t)o * 512 + lane * 16)[c];
    p += a.x*w.x + a.y*w.y + a.z*w.z + a.w*w.w;
  }
  #pragma unroll
  for (int s = 16; s >= 1; s >>= 1) p += __shfl_xor(p, s, 32);
  if (lane == 0) vn_up[o] = p + v2b[o];
}

__global__ void k_vn_ln(float* __restrict__ vn_cur, const float* __restrict__ vn_up,
                        const float* __restrict__ g2, const float* __restrict__ be2) {
  __shared__ float s_red[8];
  const int t = threadIdx.x;
  float r = vn_cur[t] + vn_up[t];
  float s1 = r, s2 = r * r;
  #pragma unroll
  for (int o = 32; o >= 1; o >>= 1) { s1 += __shfl_xor(s1, o); s2 += __shfl_xor(s2, o); }
  if ((t & 63) == 0) { s_red[t >> 6] = s1; s_red[4 + (t >> 6)] = s2; }
  __syncthreads();
  s1 = s_red[0] + s_red[1] + s_red[2] + s_red[3];
  s2 = s_red[4] + s_red[5] + s_red[6] + s_red[7];
  float mean = s1 * (1.0f / HID);
  float var  = s2 * (1.0f / HID) - mean * mean;
  vn_cur[t] = (r - mean) * rsqrtf(var + EPSLN) * g2[t] + be2[t];
}

__global__ void k_vn_ctr(const float* __restrict__ vn_cur,
                         const float* __restrict__ U1, const float* __restrict__ u1b,
                         float* __restrict__ vn_ctr) {
  const int o = blockIdx.x * 8 + (threadIdx.x >> 5);
  const int lane = threadIdx.x & 31;
  const float4* vp = reinterpret_cast<const float4*>(vn_cur + lane * 8);
  float4 a0 = vp[0], a1 = vp[1];
  const float4* wp = reinterpret_cast<const float4*>(U1 + (size_t)o * 512 + 256 + lane * 8);
  float4 w0 = wp[0], w1 = wp[1];
  float p = a0.x*w0.x + a0.y*w0.y + a0.z*w0.z + a0.w*w0.w
          + a1.x*w1.x + a1.y*w1.y + a1.z*w1.z + a1.w*w1.w;
  #pragma unroll
  for (int s = 16; s >= 1; s >>= 1) p += __shfl_xor(p, s, 32);
  if (lane == 0) vn_ctr[o] = p + u1b[o];
}

// ---------------- residual + LN ----------------
__global__ __launch_bounds__(256) void k_ln_res(
    float* __restrict__ x, bf16* __restrict__ xb, const float* __restrict__ xu,
    const float* __restrict__ g_l, const float* __restrict__ b_l)
{
  __shared__ float s_red[8];
  const int t = threadIdx.x, i = blockIdx.x;
  float r = x[(size_t)i * HID + t] + xu[(size_t)i * HID + t];
  float s1 = r, s2 = r * r;
  #pragma unroll
  for (int o = 32; o >= 1; o >>= 1) { s1 += __shfl_xor(s1, o); s2 += __shfl_xor(s2, o); }
  if ((t & 63) == 0) { s_red[t >> 6] = s1; s_red[4 + (t >> 6)] = s2; }
  __syncthreads();
  s1 = s_red[0] + s_red[1] + s_red[2] + s_red[3];
  s2 = s_red[4] + s_red[5] + s_red[6] + s_red[7];
  float mean = s1 * (1.0f / HID);
  float var  = s2 * (1.0f / HID) - mean * mean;
  float o = (r - mean) * rsqrtf(var + EPSLN) * g_l[t] + b_l[t];
  x [(size_t)i * HID + t] = o;
  xb[(size_t)i * HID + t] = (bf16)o;
}

// ---------------- final tiny head ----------------
__global__ void k_final(const float* __restrict__ g, const float* __restrict__ O2,
                        const float* __restrict__ o2b, float* __restrict__ out) {
  int tid = blockIdx.x * 256 + threadIdx.x;
  if (tid >= N_NODES * NCLS) return;
  int n = tid >> 1, j = tid & 1;
  const float* gr = g + (size_t)n * HID;
  const float* w  = O2 + (size_t)j * HID;
  float d = o2b[j];
  for (int k = 0; k < HID; ++k) d = fmaf(gr[k], w[k], d);
  out[tid] = d;
}

extern "C" void kernel_launch(void* const* d_in, const int* in_sizes, int n_in,
                              void* d_out, int out_size, void* d_ws, size_t ws_size,
                              hipStream_t stream)
{
  const float* x_in  = (const float*)d_in[0];
  const int*   ei    = (const int*)  d_in[1];
  const float* W_in  = (const float*)d_in[2];
  const float* b_in  = (const float*)d_in[3];
  const float* vnode = (const float*)d_in[4];
  const float* Wl    = (const float*)d_in[5];
  const float* bl    = (const float*)d_in[6];
  const float* Wr    = (const float*)d_in[7];
  const float* br    = (const float*)d_in[8];
  const float* att   = (const float*)d_in[9];
  const float* gbias = (const float*)d_in[10];
  const float* V1    = (const float*)d_in[11];
  const float* v1b   = (const float*)d_in[12];
  const float* V2    = (const float*)d_in[13];
  const float* v2b   = (const float*)d_in[14];
  const float* U1    = (const float*)d_in[15];
  const float* u1b   = (const float*)d_in[16];
  const float* U2    = (const float*)d_in[17];
  const float* u2b   = (const float*)d_in[18];
  const float* g1    = (const float*)d_in[19];
  const float* be1   = (const float*)d_in[20];
  const float* g2    = (const float*)d_in[21];
  const float* be2   = (const float*)d_in[22];
  const float* g3    = (const float*)d_in[23];
  const float* be3   = (const float*)d_in[24];
  const float* O1    = (const float*)d_in[25];
  const float* o1b   = (const float*)d_in[26];
  const float* O2    = (const float*)d_in[27];
  const float* o2b   = (const float*)d_in[28];
  float* out = (float*)d_out;

  char* ws = (char*)d_ws;
  size_t cur = 0;
  auto alloc = [&](size_t bytes) -> char* {
    char* p = ws + cur;
    cur = (cur + bytes + 255) & ~(size_t)255;
    return p;
  };
  float* x        = (float*)alloc((size_t)M_PAD * HID * 4);
  bf16*  xb       = (bf16*) alloc((size_t)M_PAD * HID * 2);
  bf16*  xlr      = (bf16*) alloc((size_t)M_PAD * 4096 * 2);
  bf16*  h1       = (bf16*) alloc((size_t)M_PAD * 2 * HID * 2);
  float* xu       = (float*)alloc((size_t)M_PAD * HID * 4);
  bf16*  Wlrb     = (bf16*) alloc((size_t)NLAYER * 4096 * HID * 2);
  float* blr      = (float*)alloc((size_t)NLAYER * 4096 * 4);
  bf16*  U1b      = (bf16*) alloc((size_t)NLAYER * 2 * HID * 2 * HID * 2);
  bf16*  U2b      = (bf16*) alloc((size_t)NLAYER * HID * 2 * HID * 2);
  bf16*  O1b      = (bf16*) alloc((size_t)HID * HID * 2);
  bf16*  Winb     = (bf16*) alloc((size_t)HID * DIM_IN * 2);
  int*   deg      = (int*)  alloc((size_t)N_NODES * 4);
  int*   offs     = (int*)  alloc((size_t)(N_NODES + 1) * 4);
  int*   fill     = (int*)  alloc((size_t)N_NODES * 4);
  int*   adj      = (int*)  alloc((size_t)ETOT * 4);
  float* vn_accum = (float*)alloc(HID * 4);
  float* vn_cur   = (float*)alloc(HID * 4);
  float* vn_ctr   = (float*)alloc(2 * HID * 4);
  float* z1buf    = (float*)alloc(2 * HID * 4);
  float* vn_up    = (float*)alloc(HID * 4);

  // x_in as padded bf16 reuses xlr space (xlr unused until first layer GEMM)
  bf16* x_in_b = xlr;

  // CSR build
  hipMemsetAsync(deg, 0, (size_t)N_NODES * 4, stream);
  hipMemsetAsync(fill, 0, (size_t)N_NODES * 4, stream);
  k_count<<<(ETOT + 255) / 256, 256, 0, stream>>>(ei, deg);
  k_scan<<<1, 1024, 0, stream>>>(deg, offs);
  k_scatter<<<(ETOT + 255) / 256, 256, 0, stream>>>(ei, offs, fill, adj);
  k_init_vn<<<1, 256, 0, stream>>>(vnode, vn_cur);

  // weight prep
  k_catw<<<(NLAYER * 4096 * 256 / 8 + 255) / 256, 256, 0, stream>>>(Wl, Wr, Wlrb);
  k_catb<<<(NLAYER * 4096 + 255) / 256, 256, 0, stream>>>(bl, br, blr);
  k_f2b<<<256, 256, 0, stream>>>(U1, U1b, NLAYER * 2 * HID * 2 * HID / 4);
  k_f2b<<<128, 256, 0, stream>>>(U2, U2b, NLAYER * HID * 2 * HID / 4);
  k_f2b<<<64, 256, 0, stream>>>(O1, O1b, HID * HID / 4);
  k_f2b<<<64, 256, 0, stream>>>(W_in, Winb, HID * DIM_IN / 4);
  k_f2b<<<512, 256, 0, stream>>>(x_in, x_in_b, N_NODES * DIM_IN / 4);

  const int MT64 = M_PAD / 64;    // 158
  const int MT   = M_PAD / 128;   // 79

  // input projection: x (fp32) + xb (bf16) in one GEMM (64x64 tiles, 632 blocks)
  k_gemm64<0, true, true><<<MT64 * 4, 256, 0, stream>>>(
      x_in_b, DIM_IN, Winb, DIM_IN, b_in, xb, x, HID, N_NODES, DIM_IN, 4);

  for (int i = 0; i < NLAYER; ++i) {
    const bf16* Wlrb_i = Wlrb + (size_t)i * 4096 * HID;
    const bf16* U1b_i  = U1b + (size_t)i * 2 * HID * 2 * HID;
    const bf16* U2b_i  = U2b + (size_t)i * HID * 2 * HID;

    // xlr = x @ [Wl;Wr]^T + [bl;br]   (128x128 tiles, 2528 blocks)
    k_gemm2<0, true, false><<<MT * 32, 256, 0, stream>>>(
        xb, HID, Wlrb_i, HID, blr + (size_t)i * 4096, xlr, nullptr, 4096, N_NODES, HID, 32);

    k_node_attn<<<N_NODES, 256, 0, stream>>>(x, xb, xlr, offs, adj,
        att + (size_t)i * HC, gbias + (size_t)i * HID,
        g1 + (size_t)i * HID, be1 + (size_t)i * HID);

    hipMemsetAsync(vn_accum, 0, HID * 4, stream);
    k_colmean<<<200, 256, 0, stream>>>(x, vn_accum);
    k_vn_gemv1<<<64, 256, 0, stream>>>(vn_accum,
        V1 + (size_t)i * 2 * HID * HID, v1b + (size_t)i * 2 * HID, z1buf);
    k_vn_gemv2<<<32, 256, 0, stream>>>(z1buf,
        V2 + (size_t)i * HID * 2 * HID, v2b + (size_t)i * HID, vn_up);
    k_vn_ln<<<1, 256, 0, stream>>>(vn_cur, vn_up,
        g2 + (size_t)i * HID, be2 + (size_t)i * HID);
    k_vn_ctr<<<64, 256, 0, stream>>>(vn_cur,
        U1 + (size_t)i * 2 * HID * 2 * HID, u1b + (size_t)i * 2 * HID, vn_ctr);

    // h1 = gelu(x @ U1[:, :256]^T + vn_ctr)  (bf16 out, 64x64 tiles, 1264 blocks)
    k_gemm64<1, true, false><<<MT64 * 8, 256, 0, stream>>>(
        xb, HID, U1b_i, 2 * HID, vn_ctr, h1, nullptr, 2 * HID, N_NODES, HID, 8);
    // xu = h1 @ U2^T + u2b  (fp32 out, 64x64 tiles, 632 blocks)
    k_gemm64<0, false, true><<<MT64 * 4, 256, 0, stream>>>(
        h1, 2 * HID, U2b_i, 2 * HID, u2b + (size_t)i * HID, nullptr, xu, HID, N_NODES, 2 * HID, 4);

    k_ln_res<<<N_NODES, 256, 0, stream>>>(x, xb, xu, g3 + (size_t)i * HID, be3 + (size_t)i * HID);
  }

  // final head: gelu(x @ O1^T + o1b) -> xu (fp32), then tiny N=2 matvec
  k_gemm64<1, false, true><<<MT64 * 4, 256, 0, stream>>>(
      xb, HID, O1b, HID, o1b, nullptr, xu, HID, N_NODES, HID, 4);
  k_final<<<(N_NODES * NCLS + 255) / 256, 256, 0, stream>>>(xu, O2, o2b, out);
}

// Round 11
// 830.645 us; speedup vs baseline: 1.2272x; 1.1658x over previous
//
#include <hip/hip_runtime.h>
#include <hip/hip_bf16.h>
#include <cstdint>
#include <cstddef>

#define N_NODES 10000
#define M_PAD   10112   // N_NODES rounded up to 128
#define N_EDGES 60000
#define ETOT    70000
#define DIM_IN  768
#define HID     256
#define NHEAD   8
#define CH      256
#define HC      2048
#define NLAYER  4
#define NCLS    2
#define EPSLN   1e-5f
#define SLOPE   0.2f
#define DEG_CAP 128

typedef __bf16 bf16;
typedef __bf16 bf16x8 __attribute__((ext_vector_type(8)));
typedef float  f32x4  __attribute__((ext_vector_type(4)));

__device__ __forceinline__ float gelu_erf(float x) {
  return 0.5f * x * (1.0f + erff(x * 0.70710678118654752f));
}

// async global->LDS, 16B per lane
__device__ __forceinline__ void gl2lds16(const void* g, void* l) {
  __builtin_amdgcn_global_load_lds(
      (const __attribute__((address_space(1))) unsigned int*)g,
      (__attribute__((address_space(3))) unsigned int*)l,
      16, 0, 0);
}

// ---------------- CSR build ----------------
__global__ void k_count(const int* __restrict__ ei, int* __restrict__ deg) {
  int e = blockIdx.x * 256 + threadIdx.x;
  if (e >= ETOT) return;
  int d = (e < N_EDGES) ? ei[N_EDGES + e] : (e - N_EDGES);
  atomicAdd(&deg[d], 1);
}

__global__ void k_scan(const int* __restrict__ deg, int* __restrict__ offs) {
  __shared__ int lds[1024];
  const int t = threadIdx.x;
  const int c0 = t * 10;
  int s = 0;
  #pragma unroll
  for (int q = 0; q < 10; ++q) { int idx = c0 + q; if (idx < N_NODES) s += deg[idx]; }
  lds[t] = s;
  __syncthreads();
  for (int o = 1; o < 1024; o <<= 1) {
    int v = (t >= o) ? lds[t - o] : 0;
    __syncthreads();
    lds[t] += v;
    __syncthreads();
  }
  int run = lds[t] - s;
  #pragma unroll
  for (int q = 0; q < 10; ++q) {
    int idx = c0 + q;
    if (idx < N_NODES) { offs[idx] = run; run += deg[idx]; }
  }
  if (t == 1023) offs[N_NODES] = lds[1023];
}

__global__ void k_scatter(const int* __restrict__ ei, const int* __restrict__ offs,
                          int* __restrict__ fill, int* __restrict__ adj) {
  int e = blockIdx.x * 256 + threadIdx.x;
  if (e >= ETOT) return;
  int s, d;
  if (e < N_EDGES) { s = ei[e]; d = ei[N_EDGES + e]; } else { s = e - N_EDGES; d = s; }
  int pos = offs[d] + atomicAdd(&fill[d], 1);
  adj[pos] = s;
}

__global__ void k_init_vn(const float* __restrict__ vnode, float* __restrict__ vn_cur) {
  int t = threadIdx.x;
  if (t < HID) vn_cur[t] = vnode[t];
}

// ---------------- f32 -> bf16 convert (grid-stride, 4-wide) ----------------
__global__ void k_f2b(const float* __restrict__ src, bf16* __restrict__ dst, int n4) {
  int i = blockIdx.x * 256 + threadIdx.x;
  int stride = gridDim.x * 256;
  for (; i < n4; i += stride) {
    float4 v = reinterpret_cast<const float4*>(src)[i];
    bf16 o0 = (bf16)v.x, o1 = (bf16)v.y, o2 = (bf16)v.z, o3 = (bf16)v.w;
    ushort4 pack;
    pack.x = __builtin_bit_cast(unsigned short, o0);
    pack.y = __builtin_bit_cast(unsigned short, o1);
    pack.z = __builtin_bit_cast(unsigned short, o2);
    pack.w = __builtin_bit_cast(unsigned short, o3);
    reinterpret_cast<ushort4*>(dst)[i] = pack;
  }
}

// ---------------- concat [Wl;Wr] -> bf16 [NLAYER][4096][256] ----------------
__global__ void k_catw(const float* __restrict__ Wl, const float* __restrict__ Wr,
                       bf16* __restrict__ out) {
  int idx = blockIdx.x * 256 + threadIdx.x;        // one per 8 elements
  const int total8 = NLAYER * 4096 * 256 / 8;
  if (idx >= total8) return;
  size_t flat = (size_t)idx * 8;
  int i   = (int)(flat / (4096 * 256));
  int rem = (int)(flat % (4096 * 256));
  int r = rem >> 8;
  int k = rem & 255;
  const float* src = (r < 2048)
      ? Wl + (((size_t)i * 2048 + r) << 8) + k
      : Wr + (((size_t)i * 2048 + (r - 2048)) << 8) + k;
  const float4* p4 = reinterpret_cast<const float4*>(src);
  float4 u0 = p4[0], u1 = p4[1];
  bf16x8 ov;
  ov[0]=(bf16)u0.x; ov[1]=(bf16)u0.y; ov[2]=(bf16)u0.z; ov[3]=(bf16)u0.w;
  ov[4]=(bf16)u1.x; ov[5]=(bf16)u1.y; ov[6]=(bf16)u1.z; ov[7]=(bf16)u1.w;
  reinterpret_cast<bf16x8*>(out)[idx] = ov;
}

__global__ void k_catb(const float* __restrict__ bl, const float* __restrict__ br,
                       float* __restrict__ out) {
  int idx = blockIdx.x * 256 + threadIdx.x;        // NLAYER*4096
  if (idx >= NLAYER * 4096) return;
  int i = idx >> 12, r = idx & 4095;
  out[idx] = (r < 2048) ? bl[i * 2048 + r] : br[i * 2048 + (r - 2048)];
}

// ---------------- bf16 MFMA GEMM: 128x128 tile, BK=64, dbuf (R7 loop) + coalesced epilogue
// 1D grid, m204 bijective XCD swizzle, N-fastest. Output bf16 only.
template<int ACT>
__global__ __launch_bounds__(256) void k_gemm2(
    const bf16* __restrict__ A, int lda,
    const bf16* __restrict__ W, int ldw,
    const float* __restrict__ bias,
    bf16* __restrict__ Cb, int ldc,
    int M, int K, int NT)
{
  __shared__ bf16 smem[32768];           // As0|As1|Bs0|Bs1 (8192 each); epilogue reuses
  const int t = threadIdx.x;
  const int nwg = gridDim.x;
  const int qq = nwg >> 3, rr = nwg & 7;
  const int xcd = blockIdx.x & 7, loc = blockIdx.x >> 3;
  const int wg = (xcd < rr) ? (xcd * (qq + 1) + loc)
                            : (rr * (qq + 1) + (xcd - rr) * qq + loc);
  const int bm = (wg / NT) * 128;
  const int bn = (wg % NT) * 128;
  const int l = t & 63, w = t >> 6;
  const int wm = (w >> 1) * 64, wn = (w & 1) * 64;
  const int lr = l & 15, lg = l >> 4;
  const int sr = t >> 3;     // staging row within 32-row group
  const int ps = t & 7;      // physical 16B slot

  f32x4 acc[4][4];
  #pragma unroll
  for (int a = 0; a < 4; ++a)
    #pragma unroll
    for (int b = 0; b < 4; ++b) acc[a][b] = (f32x4){0.f, 0.f, 0.f, 0.f};

  auto stage = [&](bf16* Ad, bf16* Bd, int k0) {
    #pragma unroll
    for (int q = 0; q < 4; ++q) {
      int r = q * 32 + sr;
      int ls = ps ^ (r & 7);                       // inverse-swizzled source slot
      gl2lds16(A + (size_t)(bm + r) * lda + k0 + ls * 8, Ad + r * 64 + ps * 8);
    }
    #pragma unroll
    for (int q = 0; q < 4; ++q) {
      int r = q * 32 + sr;
      int ls = ps ^ (r & 7);
      gl2lds16(W + (size_t)(bn + r) * ldw + k0 + ls * 8, Bd + r * 64 + ps * 8);
    }
  };

  const int ntk = K >> 6;
  stage(smem, smem + 16384, 0);
  __syncthreads();
  for (int kt = 0; kt < ntk; ++kt) {
    const bf16* Acur = (kt & 1) ? smem + 8192  : smem;
    const bf16* Bcur = (kt & 1) ? smem + 24576 : smem + 16384;
    if (kt + 1 < ntk) {
      bf16* Anxt = (kt & 1) ? smem         : smem + 8192;
      bf16* Bnxt = (kt & 1) ? smem + 16384 : smem + 24576;
      stage(Anxt, Bnxt, (kt + 1) << 6);
    }
    #pragma unroll
    for (int ks = 0; ks < 2; ++ks) {
      bf16x8 af[4], bfr[4];
      #pragma unroll
      for (int mt = 0; mt < 4; ++mt) {
        int row = wm + mt * 16 + lr;
        int slot = ks * 4 + lg;
        af[mt] = *reinterpret_cast<const bf16x8*>(&Acur[row * 64 + ((slot ^ (row & 7)) * 8)]);
      }
      #pragma unroll
      for (int nt2 = 0; nt2 < 4; ++nt2) {
        int row = wn + nt2 * 16 + lr;
        int slot = ks * 4 + lg;
        bfr[nt2] = *reinterpret_cast<const bf16x8*>(&Bcur[row * 64 + ((slot ^ (row & 7)) * 8)]);
      }
      #pragma unroll
      for (int mt = 0; mt < 4; ++mt)
        #pragma unroll
        for (int nt2 = 0; nt2 < 4; ++nt2)
          acc[mt][nt2] = __builtin_amdgcn_mfma_f32_16x16x32_bf16(af[mt], bfr[nt2], acc[mt][nt2], 0, 0, 0);
    }
    __syncthreads();   // drains prefetch + protects buffer reuse (R7 structure)
  }

  // ---- coalesced epilogue: acc -> LDS [128][136] bf16 -> 16B row-contiguous stores ----
  bf16* Cs = smem;
  #pragma unroll
  for (int mt = 0; mt < 4; ++mt) {
    #pragma unroll
    for (int nt2 = 0; nt2 < 4; ++nt2) {
      int col = wn + nt2 * 16 + lr;
      float bv = bias[bn + col];
      #pragma unroll
      for (int j = 0; j < 4; ++j) {
        int row = wm + mt * 16 + lg * 4 + j;
        float vv = acc[mt][nt2][j] + bv;
        if (ACT == 1) vv = gelu_erf(vv);
        Cs[row * 136 + col] = (bf16)vv;
      }
    }
  }
  __syncthreads();
  #pragma unroll
  for (int k2 = 0; k2 < 8; ++k2) {
    int row = w * 32 + k2 * 4 + (l >> 4);
    int col = (l & 15) * 8;
    int grow = bm + row;
    if (grow < M) {
      bf16x8 v = *reinterpret_cast<const bf16x8*>(&Cs[row * 136 + col]);
      *reinterpret_cast<bf16x8*>(&Cb[(size_t)grow * ldc + bn + col]) = v;
    }
  }
}

// ---------------- bf16 MFMA GEMM: 64x64 tile, dbuf + fp32-staged coalesced epilogue ------
template<int ACT, bool WB, bool WF>
__global__ __launch_bounds__(256) void k_gemm64(
    const bf16* __restrict__ A, int lda,
    const bf16* __restrict__ W, int ldw,
    const float* __restrict__ bias,
    bf16* __restrict__ Cb, float* __restrict__ Cf, int ldc,
    int M, int K, int NT)
{
  __shared__ bf16 smem[16384];           // As0|As1|Bs0|Bs1 (4096 each); epilogue reuses
  const int t = threadIdx.x;
  const int nwg = gridDim.x;
  const int qq = nwg >> 3, rr = nwg & 7;
  const int xcd = blockIdx.x & 7, loc = blockIdx.x >> 3;
  const int wg = (xcd < rr) ? (xcd * (qq + 1) + loc)
                            : (rr * (qq + 1) + (xcd - rr) * qq + loc);
  const int bm = (wg / NT) * 64;
  const int bn = (wg % NT) * 64;
  const int l = t & 63, w = t >> 6;
  const int wm = (w >> 1) * 32, wn = (w & 1) * 32;
  const int lr = l & 15, lg = l >> 4;
  const int sr = t >> 3;     // staging row within 32-row group
  const int ps = t & 7;      // physical 16B slot

  f32x4 acc[2][2];
  #pragma unroll
  for (int a = 0; a < 2; ++a)
    #pragma unroll
    for (int b = 0; b < 2; ++b) acc[a][b] = (f32x4){0.f, 0.f, 0.f, 0.f};

  auto stage = [&](bf16* Ad, bf16* Bd, int k0) {
    #pragma unroll
    for (int q = 0; q < 2; ++q) {
      int r = q * 32 + sr;
      int ls = ps ^ (r & 7);
      gl2lds16(A + (size_t)(bm + r) * lda + k0 + ls * 8, Ad + r * 64 + ps * 8);
    }
    #pragma unroll
    for (int q = 0; q < 2; ++q) {
      int r = q * 32 + sr;
      int ls = ps ^ (r & 7);
      gl2lds16(W + (size_t)(bn + r) * ldw + k0 + ls * 8, Bd + r * 64 + ps * 8);
    }
  };

  const int ntk = K >> 6;
  stage(smem, smem + 8192, 0);
  __syncthreads();
  for (int kt = 0; kt < ntk; ++kt) {
    const bf16* Acur = (kt & 1) ? smem + 4096  : smem;
    const bf16* Bcur = (kt & 1) ? smem + 12288 : smem + 8192;
    if (kt + 1 < ntk) {
      bf16* Anxt = (kt & 1) ? smem        : smem + 4096;
      bf16* Bnxt = (kt & 1) ? smem + 8192 : smem + 12288;
      stage(Anxt, Bnxt, (kt + 1) << 6);
    }
    #pragma unroll
    for (int ks = 0; ks < 2; ++ks) {
      bf16x8 af[2], bfr[2];
      #pragma unroll
      for (int mt = 0; mt < 2; ++mt) {
        int row = wm + mt * 16 + lr;
        int slot = ks * 4 + lg;
        af[mt] = *reinterpret_cast<const bf16x8*>(&Acur[row * 64 + ((slot ^ (row & 7)) * 8)]);
      }
      #pragma unroll
      for (int nt2 = 0; nt2 < 2; ++nt2) {
        int row = wn + nt2 * 16 + lr;
        int slot = ks * 4 + lg;
        bfr[nt2] = *reinterpret_cast<const bf16x8*>(&Bcur[row * 64 + ((slot ^ (row & 7)) * 8)]);
      }
      #pragma unroll
      for (int mt = 0; mt < 2; ++mt)
        #pragma unroll
        for (int nt2 = 0; nt2 < 2; ++nt2)
          acc[mt][nt2] = __builtin_amdgcn_mfma_f32_16x16x32_bf16(af[mt], bfr[nt2], acc[mt][nt2], 0, 0, 0);
    }
    __syncthreads();
  }

  // ---- coalesced epilogue: acc -> LDS [64][68] fp32 -> row-contiguous stores ----
  float* Cs = reinterpret_cast<float*>(smem);
  #pragma unroll
  for (int mt = 0; mt < 2; ++mt) {
    #pragma unroll
    for (int nt2 = 0; nt2 < 2; ++nt2) {
      int col = wn + nt2 * 16 + lr;
      float bv = bias[bn + col];
      #pragma unroll
      for (int j = 0; j < 4; ++j) {
        int row = wm + mt * 16 + lg * 4 + j;
        float vv = acc[mt][nt2][j] + bv;
        if (ACT == 1) vv = gelu_erf(vv);
        Cs[row * 68 + col] = vv;
      }
    }
  }
  __syncthreads();
  #pragma unroll
  for (int k2 = 0; k2 < 4; ++k2) {
    int row = w * 16 + k2 * 4 + (l >> 4);
    int col = (l & 15) * 4;
    int grow = bm + row;
    if (grow < M) {
      float4 v = *reinterpret_cast<const float4*>(&Cs[row * 68 + col]);
      if (WF) *reinterpret_cast<float4*>(&Cf[(size_t)grow * ldc + bn + col]) = v;
      if (WB) {
        ushort4 pack;
        pack.x = __builtin_bit_cast(unsigned short, (bf16)v.x);
        pack.y = __builtin_bit_cast(unsigned short, (bf16)v.y);
        pack.z = __builtin_bit_cast(unsigned short, (bf16)v.z);
        pack.w = __builtin_bit_cast(unsigned short, (bf16)v.w);
        *reinterpret_cast<ushort4*>(&Cb[(size_t)grow * ldc + bn + col]) = pack;
      }
    }
  }
}

// ---------------- fused GATv2 attention (online softmax, defer-max) + mean + res + LN ----
// leaky(z) with slope 0.2 == 0.6z + 0.4|z| exactly -> fold into dot with pre-scaled att.
__global__ __launch_bounds__(256) void k_node_attn(
    float* __restrict__ x, bf16* __restrict__ xb,
    const bf16* __restrict__ xlr,   // [M_PAD][4096]: xl cols 0..2047, xr cols 2048..4095
    const int* __restrict__ offs, const int* __restrict__ adj,
    const float* __restrict__ att_l, const float* __restrict__ gbias_l,
    const float* __restrict__ g_l, const float* __restrict__ b_l)
{
  __shared__ int   s_src[DEG_CAP];
  __shared__ float s_agg[HC];
  __shared__ float s_red[8];

  const int t = threadIdx.x;
  const int i = blockIdx.x;
  const int start = offs[i];
  int deg = offs[i + 1] - start;
  if (deg > DEG_CAP) deg = DEG_CAP;

  for (int j = t; j < deg; j += 256) s_src[j] = adj[start + j];

  float xr_reg[8], a6[8], a4[8];
  {
    bf16x8 xv = *reinterpret_cast<const bf16x8*>(xlr + (size_t)i * 4096 + 2048 + 8 * t);
    #pragma unroll
    for (int q = 0; q < 8; ++q) xr_reg[q] = (float)xv[q];
    const float4* ap = reinterpret_cast<const float4*>(att_l + 8 * t);
    float4 a0 = ap[0], a1 = ap[1];
    a6[0]=0.6f*a0.x; a6[1]=0.6f*a0.y; a6[2]=0.6f*a0.z; a6[3]=0.6f*a0.w;
    a6[4]=0.6f*a1.x; a6[5]=0.6f*a1.y; a6[6]=0.6f*a1.z; a6[7]=0.6f*a1.w;
    a4[0]=0.4f*a0.x; a4[1]=0.4f*a0.y; a4[2]=0.4f*a0.z; a4[3]=0.4f*a0.w;
    a4[4]=0.4f*a1.x; a4[5]=0.4f*a1.y; a4[6]=0.4f*a1.z; a4[7]=0.4f*a1.w;
  }
  __syncthreads();

  // online softmax with defer-max rescale
  float m = -1e30f, ssum = 0.f;
  float acc[8];
  #pragma unroll
  for (int q = 0; q < 8; ++q) acc[q] = 0.f;

  for (int j = 0; j < deg; ++j) {
    bf16x8 xv = *reinterpret_cast<const bf16x8*>(xlr + (size_t)s_src[j] * 4096 + 8 * t);
    float xf[8];
    float p = 0.f;
    #pragma unroll
    for (int q = 0; q < 8; ++q) {
      xf[q] = (float)xv[q];
      float z = xf[q] + xr_reg[q];
      p = fmaf(a6[q], z, p);
      p = fmaf(a4[q], fabsf(z), p);   // |z| is a free src modifier
    }
    #pragma unroll
    for (int o = 16; o >= 1; o >>= 1) p += __shfl_xor(p, o, 32);
    if (__any(p > m)) {                 // rescale only when some head's max grows
      float mn = fmaxf(m, p);
      float scale = __expf(m - mn);     // ==1 for heads whose max didn't grow
      ssum *= scale;
      #pragma unroll
      for (int q = 0; q < 8; ++q) acc[q] *= scale;
      m = mn;
    }
    float a = __expf(p - m);
    ssum += a;
    #pragma unroll
    for (int q = 0; q < 8; ++q) acc[q] = fmaf(a, xf[q], acc[q]);
  }
  float inv = 1.0f / ssum;
  #pragma unroll
  for (int q = 0; q < 8; ++q) s_agg[8 * t + q] = acc[q] * inv;
  __syncthreads();

  float xloc = 0.f;
  #pragma unroll
  for (int hh = 0; hh < NHEAD; ++hh) xloc += s_agg[hh * CH + t];
  xloc = xloc * (1.0f / NHEAD) + gbias_l[t];
  float r = x[(size_t)i * HID + t] + xloc;

  float s1 = r, s2 = r * r;
  #pragma unroll
  for (int o = 32; o >= 1; o >>= 1) { s1 += __shfl_xor(s1, o); s2 += __shfl_xor(s2, o); }
  if ((t & 63) == 0) { s_red[t >> 6] = s1; s_red[4 + (t >> 6)] = s2; }
  __syncthreads();
  s1 = s_red[0] + s_red[1] + s_red[2] + s_red[3];
  s2 = s_red[4] + s_red[5] + s_red[6] + s_red[7];
  float mean = s1 * (1.0f / HID);
  float var  = s2 * (1.0f / HID) - mean * mean;
  float o = (r - mean) * rsqrtf(var + EPSLN) * g_l[t] + b_l[t];
  x [(size_t)i * HID + t] = o;
  xb[(size_t)i * HID + t] = (bf16)o;
}

// ---------------- column mean partials ----------------
__global__ void k_colmean(const float* __restrict__ x, float* __restrict__ accum) {
  const int t = threadIdx.x, b = blockIdx.x;
  float s = 0.f;
  for (int r = b * 50; r < (b + 1) * 50; ++r) s += x[(size_t)r * HID + t];
  atomicAdd(&accum[t], s);
}

// ---------------- vn path: multi-block GEMVs + tiny LN ----------------
__global__ void k_vn_gemv1(const float* __restrict__ vn_accum,
                           const float* __restrict__ V1, const float* __restrict__ v1b,
                           float* __restrict__ z1) {
  const int o = blockIdx.x * 8 + (threadIdx.x >> 5);
  const int lane = threadIdx.x & 31;
  const float4* vp = reinterpret_cast<const float4*>(vn_accum + lane * 8);
  float4 a0 = vp[0], a1 = vp[1];
  const float4* wp = reinterpret_cast<const float4*>(V1 + (size_t)o * 256 + lane * 8);
  float4 w0 = wp[0], w1 = wp[1];
  float p = a0.x*w0.x + a0.y*w0.y + a0.z*w0.z + a0.w*w0.w
          + a1.x*w1.x + a1.y*w1.y + a1.z*w1.z + a1.w*w1.w;
  #pragma unroll
  for (int s = 16; s >= 1; s >>= 1) p += __shfl_xor(p, s, 32);
  if (lane == 0) z1[o] = gelu_erf(p * (1.0f / (float)N_NODES) + v1b[o]);
}

__global__ void k_vn_gemv2(const float* __restrict__ z1,
                           const float* __restrict__ V2, const float* __restrict__ v2b,
                           float* __restrict__ vn_up) {
  const int o = blockIdx.x * 8 + (threadIdx.x >> 5);
  const int lane = threadIdx.x & 31;
  float p = 0.f;
  #pragma unroll
  for (int c = 0; c < 4; ++c) {
    float4 a = reinterpret_cast<const float4*>(z1 + lane * 16)[c];
    float4 w = reinterpret_cast<const float4*>(V2 + (size_t)o * 512 + lane * 16)[c];
    p += a.x*w.x + a.y*w.y + a.z*w.z + a.w*w.w;
  }
  #pragma unroll
  for (int s = 16; s >= 1; s >>= 1) p += __shfl_xor(p, s, 32);
  if (lane == 0) vn_up[o] = p + v2b[o];
}

__global__ void k_vn_ln(float* __restrict__ vn_cur, const float* __restrict__ vn_up,
                        const float* __restrict__ g2, const float* __restrict__ be2) {
  __shared__ float s_red[8];
  const int t = threadIdx.x;
  float r = vn_cur[t] + vn_up[t];
  float s1 = r, s2 = r * r;
  #pragma unroll
  for (int o = 32; o >= 1; o >>= 1) { s1 += __shfl_xor(s1, o); s2 += __shfl_xor(s2, o); }
  if ((t & 63) == 0) { s_red[t >> 6] = s1; s_red[4 + (t >> 6)] = s2; }
  __syncthreads();
  s1 = s_red[0] + s_red[1] + s_red[2] + s_red[3];
  s2 = s_red[4] + s_red[5] + s_red[6] + s_red[7];
  float mean = s1 * (1.0f / HID);
  float var  = s2 * (1.0f / HID) - mean * mean;
  vn_cur[t] = (r - mean) * rsqrtf(var + EPSLN) * g2[t] + be2[t];
}

__global__ void k_vn_ctr(const float* __restrict__ vn_cur,
                         const float* __restrict__ U1, const float* __restrict__ u1b,
                         float* __restrict__ vn_ctr) {
  const int o = blockIdx.x * 8 + (threadIdx.x >> 5);
  const int lane = threadIdx.x & 31;
  const float4* vp = reinterpret_cast<const float4*>(vn_cur + lane * 8);
  float4 a0 = vp[0], a1 = vp[1];
  const float4* wp = reinterpret_cast<const float4*>(U1 + (size_t)o * 512 + 256 + lane * 8);
  float4 w0 = wp[0], w1 = wp[1];
  float p = a0.x*w0.x + a0.y*w0.y + a0.z*w0.z + a0.w*w0.w
          + a1.x*w1.x + a1.y*w1.y + a1.z*w1.z + a1.w*w1.w;
  #pragma unroll
  for (int s = 16; s >= 1; s >>= 1) p += __shfl_xor(p, s, 32);
  if (lane == 0) vn_ctr[o] = p + u1b[o];
}

// ---------------- residual + LN ----------------
__global__ __launch_bounds__(256) void k_ln_res(
    float* __restrict__ x, bf16* __restrict__ xb, const float* __restrict__ xu,
    const float* __restrict__ g_l, const float* __restrict__ b_l)
{
  __shared__ float s_red[8];
  const int t = threadIdx.x, i = blockIdx.x;
  float r = x[(size_t)i * HID + t] + xu[(size_t)i * HID + t];
  float s1 = r, s2 = r * r;
  #pragma unroll
  for (int o = 32; o >= 1; o >>= 1) { s1 += __shfl_xor(s1, o); s2 += __shfl_xor(s2, o); }
  if ((t & 63) == 0) { s_red[t >> 6] = s1; s_red[4 + (t >> 6)] = s2; }
  __syncthreads();
  s1 = s_red[0] + s_red[1] + s_red[2] + s_red[3];
  s2 = s_red[4] + s_red[5] + s_red[6] + s_red[7];
  float mean = s1 * (1.0f / HID);
  float var  = s2 * (1.0f / HID) - mean * mean;
  float o = (r - mean) * rsqrtf(var + EPSLN) * g_l[t] + b_l[t];
  x [(size_t)i * HID + t] = o;
  xb[(size_t)i * HID + t] = (bf16)o;
}

// ---------------- final tiny head ----------------
__global__ void k_final(const float* __restrict__ g, const float* __restrict__ O2,
                        const float* __restrict__ o2b, float* __restrict__ out) {
  int tid = blockIdx.x * 256 + threadIdx.x;
  if (tid >= N_NODES * NCLS) return;
  int n = tid >> 1, j = tid & 1;
  const float* gr = g + (size_t)n * HID;
  const float* w  = O2 + (size_t)j * HID;
  float d = o2b[j];
  for (int k = 0; k < HID; ++k) d = fmaf(gr[k], w[k], d);
  out[tid] = d;
}

extern "C" void kernel_launch(void* const* d_in, const int* in_sizes, int n_in,
                              void* d_out, int out_size, void* d_ws, size_t ws_size,
                              hipStream_t stream)
{
  const float* x_in  = (const float*)d_in[0];
  const int*   ei    = (const int*)  d_in[1];
  const float* W_in  = (const float*)d_in[2];
  const float* b_in  = (const float*)d_in[3];
  const float* vnode = (const float*)d_in[4];
  const float* Wl    = (const float*)d_in[5];
  const float* bl    = (const float*)d_in[6];
  const float* Wr    = (const float*)d_in[7];
  const float* br    = (const float*)d_in[8];
  const float* att   = (const float*)d_in[9];
  const float* gbias = (const float*)d_in[10];
  const float* V1    = (const float*)d_in[11];
  const float* v1b   = (const float*)d_in[12];
  const float* V2    = (const float*)d_in[13];
  const float* v2b   = (const float*)d_in[14];
  const float* U1    = (const float*)d_in[15];
  const float* u1b   = (const float*)d_in[16];
  const float* U2    = (const float*)d_in[17];
  const float* u2b   = (const float*)d_in[18];
  const float* g1    = (const float*)d_in[19];
  const float* be1   = (const float*)d_in[20];
  const float* g2    = (const float*)d_in[21];
  const float* be2   = (const float*)d_in[22];
  const float* g3    = (const float*)d_in[23];
  const float* be3   = (const float*)d_in[24];
  const float* O1    = (const float*)d_in[25];
  const float* o1b   = (const float*)d_in[26];
  const float* O2    = (const float*)d_in[27];
  const float* o2b   = (const float*)d_in[28];
  float* out = (float*)d_out;

  char* ws = (char*)d_ws;
  size_t cur = 0;
  auto alloc = [&](size_t bytes) -> char* {
    char* p = ws + cur;
    cur = (cur + bytes + 255) & ~(size_t)255;
    return p;
  };
  float* x        = (float*)alloc((size_t)M_PAD * HID * 4);
  bf16*  xb       = (bf16*) alloc((size_t)M_PAD * HID * 2);
  bf16*  xlr      = (bf16*) alloc((size_t)M_PAD * 4096 * 2);
  bf16*  h1       = (bf16*) alloc((size_t)M_PAD * 2 * HID * 2);
  float* xu       = (float*)alloc((size_t)M_PAD * HID * 4);
  bf16*  Wlrb     = (bf16*) alloc((size_t)NLAYER * 4096 * HID * 2);
  float* blr      = (float*)alloc((size_t)NLAYER * 4096 * 4);
  bf16*  U1b      = (bf16*) alloc((size_t)NLAYER * 2 * HID * 2 * HID * 2);
  bf16*  U2b      = (bf16*) alloc((size_t)NLAYER * HID * 2 * HID * 2);
  bf16*  O1b      = (bf16*) alloc((size_t)HID * HID * 2);
  bf16*  Winb     = (bf16*) alloc((size_t)HID * DIM_IN * 2);
  int*   deg      = (int*)  alloc((size_t)N_NODES * 4);
  int*   offs     = (int*)  alloc((size_t)(N_NODES + 1) * 4);
  int*   fill     = (int*)  alloc((size_t)N_NODES * 4);
  int*   adj      = (int*)  alloc((size_t)ETOT * 4);
  float* vn_accum = (float*)alloc(HID * 4);
  float* vn_cur   = (float*)alloc(HID * 4);
  float* vn_ctr   = (float*)alloc(2 * HID * 4);
  float* z1buf    = (float*)alloc(2 * HID * 4);
  float* vn_up    = (float*)alloc(HID * 4);

  // x_in as padded bf16 reuses xlr space (xlr unused until first layer GEMM)
  bf16* x_in_b = xlr;

  // CSR build
  hipMemsetAsync(deg, 0, (size_t)N_NODES * 4, stream);
  hipMemsetAsync(fill, 0, (size_t)N_NODES * 4, stream);
  k_count<<<(ETOT + 255) / 256, 256, 0, stream>>>(ei, deg);
  k_scan<<<1, 1024, 0, stream>>>(deg, offs);
  k_scatter<<<(ETOT + 255) / 256, 256, 0, stream>>>(ei, offs, fill, adj);
  k_init_vn<<<1, 256, 0, stream>>>(vnode, vn_cur);

  // weight prep
  k_catw<<<(NLAYER * 4096 * 256 / 8 + 255) / 256, 256, 0, stream>>>(Wl, Wr, Wlrb);
  k_catb<<<(NLAYER * 4096 + 255) / 256, 256, 0, stream>>>(bl, br, blr);
  k_f2b<<<256, 256, 0, stream>>>(U1, U1b, NLAYER * 2 * HID * 2 * HID / 4);
  k_f2b<<<128, 256, 0, stream>>>(U2, U2b, NLAYER * HID * 2 * HID / 4);
  k_f2b<<<64, 256, 0, stream>>>(O1, O1b, HID * HID / 4);
  k_f2b<<<64, 256, 0, stream>>>(W_in, Winb, HID * DIM_IN / 4);
  k_f2b<<<512, 256, 0, stream>>>(x_in, x_in_b, N_NODES * DIM_IN / 4);

  const int MT64 = M_PAD / 64;    // 158
  const int MT   = M_PAD / 128;   // 79

  // input projection: x (fp32) + xb (bf16) in one GEMM (64x64 tiles, 632 blocks)
  k_gemm64<0, true, true><<<MT64 * 4, 256, 0, stream>>>(
      x_in_b, DIM_IN, Winb, DIM_IN, b_in, xb, x, HID, N_NODES, DIM_IN, 4);

  for (int i = 0; i < NLAYER; ++i) {
    const bf16* Wlrb_i = Wlrb + (size_t)i * 4096 * HID;
    const bf16* U1b_i  = U1b + (size_t)i * 2 * HID * 2 * HID;
    const bf16* U2b_i  = U2b + (size_t)i * HID * 2 * HID;

    // xlr = x @ [Wl;Wr]^T + [bl;br]   (128x128 tiles, 2528 blocks)
    k_gemm2<0><<<MT * 32, 256, 0, stream>>>(
        xb, HID, Wlrb_i, HID, blr + (size_t)i * 4096, xlr, 4096, N_NODES, HID, 32);

    k_node_attn<<<N_NODES, 256, 0, stream>>>(x, xb, xlr, offs, adj,
        att + (size_t)i * HC, gbias + (size_t)i * HID,
        g1 + (size_t)i * HID, be1 + (size_t)i * HID);

    hipMemsetAsync(vn_accum, 0, HID * 4, stream);
    k_colmean<<<200, 256, 0, stream>>>(x, vn_accum);
    k_vn_gemv1<<<64, 256, 0, stream>>>(vn_accum,
        V1 + (size_t)i * 2 * HID * HID, v1b + (size_t)i * 2 * HID, z1buf);
    k_vn_gemv2<<<32, 256, 0, stream>>>(z1buf,
        V2 + (size_t)i * HID * 2 * HID, v2b + (size_t)i * HID, vn_up);
    k_vn_ln<<<1, 256, 0, stream>>>(vn_cur, vn_up,
        g2 + (size_t)i * HID, be2 + (size_t)i * HID);
    k_vn_ctr<<<64, 256, 0, stream>>>(vn_cur,
        U1 + (size_t)i * 2 * HID * 2 * HID, u1b + (size_t)i * 2 * HID, vn_ctr);

    // h1 = gelu(x @ U1[:, :256]^T + vn_ctr)  (bf16 out, 64x64 tiles, 1264 blocks)
    k_gemm64<1, true, false><<<MT64 * 8, 256, 0, stream>>>(
        xb, HID, U1b_i, 2 * HID, vn_ctr, h1, nullptr, 2 * HID, N_NODES, HID, 8);
    // xu = h1 @ U2^T + u2b  (fp32 out, 64x64 tiles, 632 blocks)
    k_gemm64<0, false, true><<<MT64 * 4, 256, 0, stream>>>(
        h1, 2 * HID, U2b_i, 2 * HID, u2b + (size_t)i * HID, nullptr, xu, HID, N_NODES, 2 * HID, 4);

    k_ln_res<<<N_NODES, 256, 0, stream>>>(x, xb, xu, g3 + (size_t)i * HID, be3 + (size_t)i * HID);
  }

  // final head: gelu(x @ O1^T + o1b) -> xu (fp32), then tiny N=2 matvec
  k_gemm64<1, false, true><<<MT64 * 4, 256, 0, stream>>>(
      xb, HID, O1b, HID, o1b, nullptr, xu, HID, N_NODES, HID, 4);
  k_final<<<(N_NODES * NCLS + 255) / 256, 256, 0, stream>>>(xu, O2, o2b, out);
}